// Round 1
// baseline (1321.791 us; speedup 1.0000x reference)
//
#include <hip/hip_runtime.h>
#include <hip/hip_bf16.h>

typedef __bf16 bf16_t;
typedef __bf16 bf16x4 __attribute__((ext_vector_type(4)));
typedef __bf16 bf16x8 __attribute__((ext_vector_type(8)));
typedef float  f32x4  __attribute__((ext_vector_type(4)));

#define NH    6
#define CH    192
#define HW    112
#define SHIFT 3

// LDS strides (bf16 elements). All chosen so row stride is a multiple of 16B
// and ds_read_b128 bank aliasing is <=2-way (free per m136).
#define XLD 200   // X/Q/K/O tiles: [64][200]
#define VLD 88    // Vt [192][88], P [64][88]

#define X_OFF   0
#define Q_OFF   (64 * XLD)            // 12800   (Q buffer doubles as O)
#define K_OFF   (Q_OFF + 64 * XLD)    // 25600
#define VT_OFF  (K_OFF + 64 * XLD)    // 38400
#define P_OFF   (VT_OFF + 192 * VLD)  // 55296
#define LDS_ELEMS (P_OFF + 64 * VLD)  // 60928 bf16
#define LDS_BYTES (LDS_ELEMS * 2)     // 121856 B  (<160 KiB/CU, 1 block/CU)

// ---- weight prep: transpose + f32->bf16 into ws ----------------------------
// Layout: wts[m][h][a][k] bf16, m in {Wq,Wk,Wv,Wo}.
//   m<3 : A-operand = W^T per head:  wts[m][h][d_out][c_in] = W[c_in][h][d_out]
//   m==3: A-operand = Wo^T per head: wts[3][h][c_out][d_in] = Wo[h][d_in][c_out]
__global__ void prep_w(const float* __restrict__ Wq, const float* __restrict__ Wk,
                       const float* __restrict__ Wv, const float* __restrict__ Wo,
                       bf16_t* __restrict__ out) {
  int idx = blockIdx.x * 256 + threadIdx.x;
  const int per = NH * CH * CH;          // 221184
  if (idx >= 4 * per) return;
  int m = idx / per, r = idx % per;
  int h = r / (CH * CH), r2 = r % (CH * CH);
  int a = r2 / CH, k = r2 % CH;
  float v;
  if (m == 0)      v = Wq[(k * NH + h) * CH + a];
  else if (m == 1) v = Wk[(k * NH + h) * CH + a];
  else if (m == 2) v = Wv[(k * NH + h) * CH + a];
  else             v = Wo[(h * CH + k) * CH + a];
  out[idx] = (bf16_t)v;
}

// ---- fused swin block: one workgroup per 7x7 window, 8 waves ---------------
__global__ __launch_bounds__(512) void swin_fused(
    const float* __restrict__ x,
    const float* __restrict__ bq, const float* __restrict__ bk,
    const float* __restrict__ bv, const float* __restrict__ bo,
    const bf16_t* __restrict__ wts,
    float* __restrict__ out) {
  extern __shared__ char smem_raw[];
  bf16_t* lds = (bf16_t*)smem_raw;
  bf16_t* Xl  = lds + X_OFF;
  bf16_t* Ql  = lds + Q_OFF;   // also O
  bf16_t* Kl  = lds + K_OFF;
  bf16_t* Vtl = lds + VT_OFF;
  bf16_t* Pl  = lds + P_OFF;

  const int tid  = threadIdx.x;
  const int wave = tid >> 6;
  const int lane = tid & 63;
  const int l15  = lane & 15;
  const int lg   = lane >> 4;          // 0..3

  const int blk = blockIdx.x;
  const int b   = blk >> 8;            // batch
  const int rem = blk & 255;           // window within batch (i*16+j)
  const int wi  = rem >> 4, wj = rem & 15;

  // zero pad rows 49..63 of X
  for (int idx = tid; idx < 15 * 100; idx += 512) {
    int row = 49 + idx / 100, c2 = (idx % 100) * 2;
    *(unsigned int*)&Xl[row * XLD + c2] = 0u;
  }
  // stage window tokens (roll -3,-3 folded into the gather), f32 -> bf16
  for (int idx = tid; idx < 49 * 48; idx += 512) {
    int t = idx / 48, q4 = idx % 48;
    int hs = wi * 7 + t / 7 + SHIFT; if (hs >= HW) hs -= HW;
    int ws2 = wj * 7 + t % 7 + SHIFT; if (ws2 >= HW) ws2 -= HW;
    const float4 v = *(const float4*)&x[(((b * HW + hs) * HW) + ws2) * CH + q4 * 4];
    bf16x4 pk = { (bf16_t)v.x, (bf16_t)v.y, (bf16_t)v.z, (bf16_t)v.w };
    *(bf16x4*)&Xl[t * XLD + q4 * 4] = pk;
  }

  f32x4 yacc[3][2] = {};                   // persistent out-proj accumulators
  const int mt0 = (wave & 3) * 3;          // m-tile base for phases C/D
  const int nt0 = (wave >> 2) * 2;         // n-tile base for phases C/D

  for (int h = 0; h < NH; ++h) {
    __syncthreads();
    // ---- Phase A: Q^T-GEMM (waves 0-3) / K^T-GEMM (waves 4-7)
    // D[d,t] = sum_c W^T[d,c] * X[t,c]; packed b64 write into [t][d] row-major.
    {
      const int w2 = wave & 3;
      const bf16_t* wt = wts + (((wave < 4 ? 0 : 1) * NH + h) * CH * CH);
      const float* bias = (wave < 4 ? bq : bk) + h * CH;
      bf16_t* dst = (wave < 4) ? Ql : Kl;
      f32x4 acc[3][4] = {};
#pragma unroll
      for (int ks = 0; ks < 6; ++ks) {
        bf16x8 af[3], bfr[4];
#pragma unroll
        for (int mi = 0; mi < 3; ++mi) {
          int d = (w2 * 3 + mi) * 16 + l15;
          af[mi] = *(const bf16x8*)&wt[d * CH + ks * 32 + lg * 8];
        }
#pragma unroll
        for (int ni = 0; ni < 4; ++ni)
          bfr[ni] = *(const bf16x8*)&Xl[(ni * 16 + l15) * XLD + ks * 32 + lg * 8];
#pragma unroll
        for (int mi = 0; mi < 3; ++mi)
#pragma unroll
          for (int ni = 0; ni < 4; ++ni)
            acc[mi][ni] = __builtin_amdgcn_mfma_f32_16x16x32_bf16(af[mi], bfr[ni], acc[mi][ni], 0, 0, 0);
      }
#pragma unroll
      for (int mi = 0; mi < 3; ++mi) {
        int d0 = (w2 * 3 + mi) * 16 + lg * 4;
        float b0 = bias[d0], b1 = bias[d0 + 1], b2 = bias[d0 + 2], b3 = bias[d0 + 3];
#pragma unroll
        for (int ni = 0; ni < 4; ++ni) {
          int t = ni * 16 + l15;
          bf16x4 pk = { (bf16_t)(acc[mi][ni][0] + b0), (bf16_t)(acc[mi][ni][1] + b1),
                        (bf16_t)(acc[mi][ni][2] + b2), (bf16_t)(acc[mi][ni][3] + b3) };
          *(bf16x4*)&dst[t * XLD + d0] = pk;
        }
      }
    }
    __syncthreads();
    // ---- Phase B: V-GEMM (waves 0-3)  ||  scores + in-register softmax (waves 4-7)
    if (wave < 4) {
      // V[t,d] = sum_c X[t,c] Wv^T[d,c]; packed write into Vt[d][t].
      const bf16_t* wt = wts + ((2 * NH + h) * CH * CH);
      const float* bias = bv + h * CH;
      f32x4 acc[4][3] = {};
#pragma unroll
      for (int ks = 0; ks < 6; ++ks) {
        bf16x8 af[4], bfr[3];
#pragma unroll
        for (int mi = 0; mi < 4; ++mi)
          af[mi] = *(const bf16x8*)&Xl[(mi * 16 + l15) * XLD + ks * 32 + lg * 8];
#pragma unroll
        for (int ni = 0; ni < 3; ++ni) {
          int d = (wave * 3 + ni) * 16 + l15;
          bfr[ni] = *(const bf16x8*)&wt[d * CH + ks * 32 + lg * 8];
        }
#pragma unroll
        for (int mi = 0; mi < 4; ++mi)
#pragma unroll
          for (int ni = 0; ni < 3; ++ni)
            acc[mi][ni] = __builtin_amdgcn_mfma_f32_16x16x32_bf16(af[mi], bfr[ni], acc[mi][ni], 0, 0, 0);
      }
#pragma unroll
      for (int ni = 0; ni < 3; ++ni) {
        int d = (wave * 3 + ni) * 16 + l15;
        float bb = bias[d];
#pragma unroll
        for (int mi = 0; mi < 4; ++mi) {
          int t0 = mi * 16 + lg * 4;
          bf16x4 pk = { (bf16_t)(acc[mi][ni][0] + bb), (bf16_t)(acc[mi][ni][1] + bb),
                        (bf16_t)(acc[mi][ni][2] + bb), (bf16_t)(acc[mi][ni][3] + bb) };
          *(bf16x4*)&Vtl[d * VLD + t0] = pk;
        }
      }
    } else {
      // S^[j,i] = sum_d K[j,d] Q[i,d]; lane owns col i, rows j -> in-register softmax over j.
      const int it = wave - 4;
      f32x4 sacc[4] = {};
#pragma unroll
      for (int ks = 0; ks < 6; ++ks) {
        bf16x8 bq8 = *(const bf16x8*)&Ql[(it * 16 + l15) * XLD + ks * 32 + lg * 8];
#pragma unroll
        for (int mj = 0; mj < 4; ++mj) {
          bf16x8 ak = *(const bf16x8*)&Kl[(mj * 16 + l15) * XLD + ks * 32 + lg * 8];
          sacc[mj] = __builtin_amdgcn_mfma_f32_16x16x32_bf16(ak, bq8, sacc[mj], 0, 0, 0);
        }
      }
      const float scale = 0.07216878364870322f;  // 1/sqrt(192)
      float mx = -1e30f;
#pragma unroll
      for (int mj = 0; mj < 4; ++mj)
#pragma unroll
        for (int r = 0; r < 4; ++r) {
          int j = mj * 16 + lg * 4 + r;
          if (j < 49) mx = fmaxf(mx, sacc[mj][r]);
        }
      mx = fmaxf(mx, __shfl_xor(mx, 16));
      mx = fmaxf(mx, __shfl_xor(mx, 32));
      float p[4][4];
      float sum = 0.f;
#pragma unroll
      for (int mj = 0; mj < 4; ++mj)
#pragma unroll
        for (int r = 0; r < 4; ++r) {
          int j = mj * 16 + lg * 4 + r;
          float e = (j < 49) ? __expf((sacc[mj][r] - mx) * scale) : 0.f;
          p[mj][r] = e;
          sum += e;
        }
      sum += __shfl_xor(sum, 16);
      sum += __shfl_xor(sum, 32);
      float inv = 1.f / sum;
      int i = it * 16 + l15;
#pragma unroll
      for (int mj = 0; mj < 4; ++mj) {
        bf16x4 pk = { (bf16_t)(p[mj][0] * inv), (bf16_t)(p[mj][1] * inv),
                      (bf16_t)(p[mj][2] * inv), (bf16_t)(p[mj][3] * inv) };
        *(bf16x4*)&Pl[i * VLD + mj * 16 + lg * 4] = pk;
      }
    }
    __syncthreads();
    // ---- Phase C: O^T-GEMM. D[d,i] = sum_j Vt[d,j] P[i,j]; packed write O[i][d] (over Q buffer).
    {
      f32x4 acc[3][2] = {};
#pragma unroll
      for (int ks = 0; ks < 2; ++ks) {
        bf16x8 af[3], bfr[2];
#pragma unroll
        for (int mi = 0; mi < 3; ++mi)
          af[mi] = *(const bf16x8*)&Vtl[((mt0 + mi) * 16 + l15) * VLD + ks * 32 + lg * 8];
#pragma unroll
        for (int ni = 0; ni < 2; ++ni)
          bfr[ni] = *(const bf16x8*)&Pl[((nt0 + ni) * 16 + l15) * VLD + ks * 32 + lg * 8];
#pragma unroll
        for (int mi = 0; mi < 3; ++mi)
#pragma unroll
          for (int ni = 0; ni < 2; ++ni)
            acc[mi][ni] = __builtin_amdgcn_mfma_f32_16x16x32_bf16(af[mi], bfr[ni], acc[mi][ni], 0, 0, 0);
      }
#pragma unroll
      for (int mi = 0; mi < 3; ++mi) {
        int d0 = (mt0 + mi) * 16 + lg * 4;
#pragma unroll
        for (int ni = 0; ni < 2; ++ni) {
          int t = (nt0 + ni) * 16 + l15;
          bf16x4 pk = { (bf16_t)acc[mi][ni][0], (bf16_t)acc[mi][ni][1],
                        (bf16_t)acc[mi][ni][2], (bf16_t)acc[mi][ni][3] };
          *(bf16x4*)&Ql[t * XLD + d0] = pk;
        }
      }
    }
    __syncthreads();
    // ---- Phase D: Y^T accumulate. yacc[c,t] += sum_d Wo^T[c,d] O[t,d].
    {
      const bf16_t* wt = wts + ((3 * NH + h) * CH * CH);
#pragma unroll
      for (int ks = 0; ks < 6; ++ks) {
        bf16x8 af[3], bfr[2];
#pragma unroll
        for (int mi = 0; mi < 3; ++mi) {
          int c = (mt0 + mi) * 16 + l15;
          af[mi] = *(const bf16x8*)&wt[c * CH + ks * 32 + lg * 8];
        }
#pragma unroll
        for (int ni = 0; ni < 2; ++ni)
          bfr[ni] = *(const bf16x8*)&Ql[((nt0 + ni) * 16 + l15) * XLD + ks * 32 + lg * 8];
#pragma unroll
        for (int mi = 0; mi < 3; ++mi)
#pragma unroll
          for (int ni = 0; ni < 2; ++ni)
            yacc[mi][ni] = __builtin_amdgcn_mfma_f32_16x16x32_bf16(af[mi], bfr[ni], yacc[mi][ni], 0, 0, 0);
      }
    }
  }

  // ---- epilogue: +bo, plain-reshape merge + roll(+3,+3), packed f32x4 stores
#pragma unroll
  for (int ni = 0; ni < 2; ++ni) {
    int t = (nt0 + ni) * 16 + l15;
    if (t < 49) {
      int pos = rem * 49 + t;
      int hp = pos / 112, wp = pos % 112;
      hp += SHIFT; if (hp >= HW) hp -= HW;
      wp += SHIFT; if (wp >= HW) wp -= HW;
      float* op = out + (((b * HW + hp) * HW) + wp) * CH;
#pragma unroll
      for (int mi = 0; mi < 3; ++mi) {
        int c0 = (mt0 + mi) * 16 + lg * 4;
        f32x4 v = yacc[mi][ni];
        v[0] += bo[c0]; v[1] += bo[c0 + 1]; v[2] += bo[c0 + 2]; v[3] += bo[c0 + 3];
        *(f32x4*)&op[c0] = v;
      }
    }
  }
}

extern "C" void kernel_launch(void* const* d_in, const int* in_sizes, int n_in,
                              void* d_out, int out_size, void* d_ws, size_t ws_size,
                              hipStream_t stream) {
  const float* x  = (const float*)d_in[0];
  const float* Wq = (const float*)d_in[1];
  const float* bq = (const float*)d_in[2];
  const float* Wk = (const float*)d_in[3];
  const float* bk = (const float*)d_in[4];
  const float* Wv = (const float*)d_in[5];
  const float* bv = (const float*)d_in[6];
  const float* Wo = (const float*)d_in[7];
  const float* bo = (const float*)d_in[8];
  float* out = (float*)d_out;
  bf16_t* wts = (bf16_t*)d_ws;   // needs 4*6*192*192*2 = 1,769,472 B of ws

  // transposed bf16 weights (idempotent, rewritten every launch)
  prep_w<<<(4 * NH * CH * CH + 255) / 256, 256, 0, stream>>>(Wq, Wk, Wv, Wo, wts);

  // allow >64KB dynamic LDS
  (void)hipFuncSetAttribute((const void*)swin_fused,
                            hipFuncAttributeMaxDynamicSharedMemorySize, LDS_BYTES);
  swin_fused<<<dim3(4096), dim3(512), LDS_BYTES, stream>>>(x, bq, bk, bv, bo, wts, out);
}